// Round 2
// baseline (38.859 us; speedup 1.0000x reference)
//
#include <hip/hip_runtime.h>
#include <hip/hip_bf16.h>

// ShufflePatches: B=32, C=3, H=W=512, P=16 -> 32x32 = 1024 patches/image.
// out[b, c, oh*16+p, ow*16+q] = x[b, c, sh*16+p, sw*16+q]
//   where s = perm[b, oh*32+ow], sh = s>>5, sw = s&31.
// Pure memory-bound permutation copy: 100.66 MB read + 100.66 MB write.
//
// Fast path exploits: grid-stride = 524288 float4 = multiple of plane size
// (65536) => per-thread, only bc (= b*3+c) varies across the 12 iterations
// (bc_i = bc0 + 8*i). All patch coordinates are loop-invariant.
// Full unroll with clustered loads maximizes MLP per wave.

__global__ __launch_bounds__(256) void ShufflePatches_fast(
    const float4* __restrict__ in,   // x as float4, 6291456 elements
    const int*    __restrict__ perm, // (32, 1024)
    float4*       __restrict__ out)
{
    constexpr int ITER   = 12;
    constexpr int STRIDE = 512 * 1024;  // 524288 float4 per sweep

    int idx = blockIdx.x * 256 + threadIdx.x;   // 0 .. 524287

    // Decompose (loop-invariant part): idx = ((bc0*512 + y)*128 + x4), bc0 in [0,8)
    int x4  = idx & 127;
    int row = idx >> 7;
    int y   = row & 511;
    int bc0 = row >> 9;

    int oh = y >> 4,  p  = y & 15;
    int ow = x4 >> 2, q4 = x4 & 3;
    int j  = (oh << 5) | ow;            // output patch index (gh-major)
    int base_pq = (p << 7) + q4;        // p*128 + q4 within source plane

    // Phase 1: all perm loads (heavily L1-cached; 192 threads share each entry)
    int s[ITER];
#pragma unroll
    for (int i = 0; i < ITER; ++i) {
        int bc = bc0 + (i << 3);
        int b  = bc / 3;                // magic-mul
        s[i] = perm[(b << 10) + j];
    }

    // Phase 2: all gathers in flight
    float4 v[ITER];
#pragma unroll
    for (int i = 0; i < ITER; ++i) {
        int bc = bc0 + (i << 3);
        int sh = s[i] >> 5, sw = s[i] & 31;
        int src = (bc << 16) + (sh << 11) + (sw << 2) + base_pq;
        v[i] = in[src];
    }

    // Phase 3: coalesced streaming stores
#pragma unroll
    for (int i = 0; i < ITER; ++i) {
        out[idx + i * STRIDE] = v[i];
    }
}

// Generic fallback (kept for safety if sizes ever differ)
__global__ __launch_bounds__(256) void ShufflePatches_generic(
    const float4* __restrict__ in,
    const int*    __restrict__ perm,
    float4*       __restrict__ out,
    int total4)
{
    int idx    = blockIdx.x * blockDim.x + threadIdx.x;
    int stride = gridDim.x * blockDim.x;
    for (int t = idx; t < total4; t += stride) {
        int x4  = t & 127;
        int row = t >> 7;
        int y   = row & 511;
        int bc  = row >> 9;
        int b   = bc / 3;
        int oh = y >> 4,  p  = y & 15;
        int ow = x4 >> 2, q4 = x4 & 3;
        int s  = perm[(b << 10) + ((oh << 5) | ow)];
        int src = (bc << 16) + ((s >> 5) << 11) + ((s & 31) << 2) + (p << 7) + q4;
        out[t] = in[src];
    }
}

extern "C" void kernel_launch(void* const* d_in, const int* in_sizes, int n_in,
                              void* d_out, int out_size, void* d_ws, size_t ws_size,
                              hipStream_t stream) {
    const float4* x    = (const float4*)d_in[0];
    const int*    perm = (const int*)d_in[1];
    float4*       out  = (float4*)d_out;

    int total4 = out_size / 4;
    if (total4 == 6291456) {
        ShufflePatches_fast<<<2048, 256, 0, stream>>>(x, perm, out);
    } else {
        ShufflePatches_generic<<<2048, 256, 0, stream>>>(x, perm, out, total4);
    }
}

// Round 4
// 34.310 us; speedup vs baseline: 1.1326x; 1.1326x over previous
//
#include <hip/hip_runtime.h>
#include <hip/hip_bf16.h>

// ShufflePatches: B=32, C=3, H=W=512, P=16 -> 32x32 = 1024 patches/image.
// out[b, c, oh*16+p, ow*16+q] = x[b, c, sh*16+p, sw*16+q]
//   where s = perm[b, oh*32+ow], sh = s>>5, sw = s&31.
// Pure memory-bound permutation copy: 100.66 MB read + 100.66 MB write.
//
// R1 (simple grid-stride loop): 34.6 us, FETCH 54 MB / WRITE 96 MB ->
// input is ~half L3-resident; output write-allocate evicts the other half.
// R4: non-temporal stores (gfx950 `nt`) via native ext_vector type (HIP's
// float4 class wrapper is rejected by the builtin).

typedef float vfloat4 __attribute__((ext_vector_type(4)));

__global__ __launch_bounds__(256) void ShufflePatches_45878840656651_kernel(
    const vfloat4* __restrict__ in,   // x as float4, 6291456 elements
    const int*     __restrict__ perm, // (32, 1024)
    vfloat4*       __restrict__ out,
    int total4)                       // 6291456
{
    int idx    = blockIdx.x * blockDim.x + threadIdx.x;
    int stride = gridDim.x * blockDim.x;
    for (int t = idx; t < total4; t += stride) {
        // Decompose output float4 index: t = ((bc*512 + y)*128 + x4)
        int x4  = t & 127;         // float4 column within row (W/4 = 128)
        int row = t >> 7;          // bc*512 + y
        int y   = row & 511;
        int bc  = row >> 9;        // b*3 + c
        int b   = bc / 3;          // compiler emits magic-mul

        int oh = y  >> 4, p  = y  & 15;
        int ow = x4 >> 2, q4 = x4 & 3;

        int j = (oh << 5) | ow;            // patch index, gh-major
        int s = perm[(b << 10) + j];       // source patch
        int sh = s >> 5;
        int sw = s & 31;

        int src = (bc << 16) + (sh << 11) + (sw << 2) + (p << 7) + q4;
        vfloat4 v = in[src];
        __builtin_nontemporal_store(v, &out[t]);
    }
}

extern "C" void kernel_launch(void* const* d_in, const int* in_sizes, int n_in,
                              void* d_out, int out_size, void* d_ws, size_t ws_size,
                              hipStream_t stream) {
    const vfloat4* x    = (const vfloat4*)d_in[0];
    const int*     perm = (const int*)d_in[1];
    vfloat4*       out  = (vfloat4*)d_out;

    int total4 = out_size / 4;  // 25165824 / 4 = 6291456
    ShufflePatches_45878840656651_kernel<<<2048, 256, 0, stream>>>(
        x, perm, out, total4);
}